// Round 6
// baseline (9.848 us; speedup 1.0000x reference)
//
#include <hip/hip_runtime.h>

#define NF 8
#define DEG 4
#define NTERMS 495
#define NQUAD 124          // ceil(495/4)
#define PF 16              // prefetch ring depth (quads)

// ---------------------------------------------------------------------------
// Compile-time combinatorics: sub-polynomial over vars x_F..x_{NF-1} with
// total degree <= REM has subcnt(F,REM) = C(NF-F+REM, REM) coefficients
// (lexicographic order, e0 slowest..e7 fastest, matching the reference
// meshgrid enumeration -- verified by the passing R2/R4/R5 kernels).
// ---------------------------------------------------------------------------
constexpr long long nCkll(int n, int k) {
    long long r = 1;
    for (int i = 1; i <= k; ++i) r = r * (n - k + i) / i;
    return r;
}
constexpr int subcnt(int F, int REM) { return (int)nCkll(NF - F + REM, REM); }

constexpr int csum(int F, int REM, int E) {
    int s = 0;
    for (int j = 0; j < E; ++j) s += subcnt(F + 1, REM - j);
    return s;
}

// ---------------------------------------------------------------------------
// Full multivariate Horner (494 FMAs, each coefficient touched once, term
// indices consumed in exact DESCENDING order: T0 = 494 .. 0).
// w quads live in a PF-deep register ring with static software prefetch:
// quad q sits in ring[q % PF]; when its last lane (.x, T0&3==0) is consumed,
// the slot is refilled with quad q-PF (ds_read_b128, compile-time offset).
// All ring indices are constexpr -> pure register file (rule #20 safe).
// ---------------------------------------------------------------------------
template<int F, int REM, int T0> struct HNode;
template<int F, int REM, int E, int T0> struct HChain;

template<int F, int REM, int T0>
struct HNode {
    static __device__ __forceinline__ float eval(const float* xs, const float4* w4,
                                                 float4 (&ring)[PF]) {
        float acc = HNode<F + 1, 0, T0 + csum(F, REM, REM)>::eval(xs, w4, ring);
        if constexpr (REM > 0)
            acc = HChain<F, REM, REM - 1, T0>::step(acc, xs, w4, ring);
        return acc;
    }
};

// leaf: coefficient at compile-time term index T0 (quad q, lane c)
template<int REM, int T0>
struct HNode<NF, REM, T0> {
    static __device__ __forceinline__ float eval(const float*, const float4* w4,
                                                 float4 (&ring)[PF]) {
        constexpr int q    = T0 >> 2;
        constexpr int c    = T0 & 3;
        constexpr int slot = q % PF;
        float v = (c == 0) ? ring[slot].x : (c == 1) ? ring[slot].y
                : (c == 2) ? ring[slot].z : ring[slot].w;
        if constexpr (c == 0 && q >= PF)
            ring[slot] = w4[q - PF];    // static prefetch, ~15 quads ahead
        return v;
    }
};

template<int F, int REM, int E, int T0>
struct HChain {
    static __device__ __forceinline__ float step(float acc, const float* xs,
                                                 const float4* w4,
                                                 float4 (&ring)[PF]) {
        float c = HNode<F + 1, REM - E, T0 + csum(F, REM, E)>::eval(xs, w4, ring);
        acc = fmaf(acc, xs[F], c);
        if constexpr (E > 0)
            return HChain<F, REM, E - 1, T0>::step(acc, xs, w4, ring);
        else
            return acc;
    }
};

// static preload of the top PF quads (123 .. 123-PF+1)
template<int I>
struct Preload {
    static __device__ __forceinline__ void run(const float4* w4, float4 (&ring)[PF]) {
        constexpr int q = NQUAD - 1 - I;
        ring[q % PF] = w4[q];
        if constexpr (I + 1 < PF) Preload<I + 1>::run(w4, ring);
    }
};

__global__ __launch_bounds__(256, 1)
void maclaurin_fused(const float* __restrict__ x,
                     const float* __restrict__ coefs,
                     const float* __restrict__ facs,
                     float* __restrict__ out, int n) {
    __shared__ __align__(16) float wl[496];   // padded to full quads

    const int tid = threadIdx.x;
    const int b   = blockIdx.x * blockDim.x + tid;

    // issue x loads first so their global latency hides under the LDS fill
    float xs[NF];
    if (b < n) {
        const float4* xp = (const float4*)(x + (size_t)b * NF);
        float4 v0 = xp[0];
        float4 v1 = xp[1];
        xs[0] = v0.x; xs[1] = v0.y; xs[2] = v0.z; xs[3] = v0.w;
        xs[4] = v1.x; xs[5] = v1.y; xs[6] = v1.z; xs[7] = v1.w;
    }

    // vectorized per-block fill: w = coefs * facs (495 floats, 123 quads + 3)
    if (tid < 123) {
        float4 c = ((const float4*)coefs)[tid];
        float4 f = ((const float4*)facs)[tid];
        ((float4*)wl)[tid] = make_float4(c.x * f.x, c.y * f.y, c.z * f.z, c.w * f.w);
    } else if (tid < 126) {
        int i = 492 + (tid - 123);
        wl[i] = coefs[i] * facs[i];
    } else if (tid == 126) {
        wl[495] = 0.0f;                 // pad lane (read by quad 123, never used)
    }
    __syncthreads();

    if (b >= n) return;

    float4 ring[PF];
    Preload<0>::run((const float4*)wl, ring);

    float r = HNode<0, DEG, 0>::eval(xs, (const float4*)wl, ring);

    out[b] = r;
}

// ---------------------------------------------------------------------------
// launch
// ---------------------------------------------------------------------------
extern "C" void kernel_launch(void* const* d_in, const int* in_sizes, int n_in,
                              void* d_out, int out_size, void* d_ws, size_t ws_size,
                              hipStream_t stream) {
    // inputs (setup_inputs order): x [B,8] f32, terms [495,8] f32,
    //                              coefs [1,495] f32, facs [495] f32
    const float* x     = (const float*)d_in[0];
    const float* coefs = (const float*)d_in[2];
    const float* facs  = (const float*)d_in[3];
    float* out = (float*)d_out;

    int n = in_sizes[0] / NF;    // 65536

    maclaurin_fused<<<(n + 255) / 256, 256, 0, stream>>>(x, coefs, facs, out, n);
}